// Round 3
// baseline (703.711 us; speedup 1.0000x reference)
//
#include <hip/hip_runtime.h>
#include <cstdint>
#include <cstddef>

typedef __attribute__((ext_vector_type(4))) float f32x4;
typedef __attribute__((ext_vector_type(8))) __bf16 bf16x8;
typedef __attribute__((ext_vector_type(4))) unsigned int u32x4;
typedef __attribute__((ext_vector_type(2))) unsigned int u32x2;

#define DEVFN static __device__ __forceinline__

// ---------------- problem dims ----------------
#define MROWS 8192    // B*L
#define DM_ 1024
#define DI_ 2048
#define NPROJ 4096    // 2*DI

// ---------------- workspace layout (bytes, 256-aligned) ----------------
#define OFF_XBF    0ull                 // bf16 x          8192x1024   (16 MB)
#define OFF_WINBF  16777216ull          // bf16 W_in       4096x1024   ( 8 MB)
#define OFF_WXBF   25165824ull          // bf16 W_x        32x2048
#define OFF_WOUTBF 25296896ull          // bf16 W_out      1024x2048   ( 4 MB)
#define OFF_WRED   29491200ull          // f32  W_red      1024x16
#define OFF_XI     29556736ull          // f32  xi         8192x2048   (64 MB)
#define OFF_RESBF  96665600ull          // bf16 res        8192x2048   (32 MB)
#define OFF_XSBF   130220032ull         // bf16 xs         8192x2048   (32 MB)
#define OFF_BC     163774464ull         // f32  bc         8192x32     ( 1 MB)
#define OFF_HS     164823040ull         // f32  hs         8192x16

DEVFN unsigned short f2bf(float f) {
  unsigned u = __float_as_uint(f);
  return (unsigned short)((u + 0x7FFFu + ((u >> 16) & 1u)) >> 16);
}

DEVFN void gload_lds16(const void* g, void* l) {
  __builtin_amdgcn_global_load_lds(
      (const __attribute__((address_space(1))) void*)g,
      (__attribute__((address_space(3))) void*)l, 16, 0, 0);
}

// ---------------- f32 -> bf16 convert (8 elems/thread) ----------------
__global__ __launch_bounds__(256) void k_f2bf(const float* __restrict__ in,
                                              unsigned short* __restrict__ out, int n8) {
  int t = blockIdx.x * 256 + threadIdx.x;
  if (t >= n8) return;
  f32x4 a = *(const f32x4*)(in + (size_t)t * 8);
  f32x4 b = *(const f32x4*)(in + (size_t)t * 8 + 4);
  u32x4 r;
  r.x = (unsigned)f2bf(a[0]) | ((unsigned)f2bf(a[1]) << 16);
  r.y = (unsigned)f2bf(a[2]) | ((unsigned)f2bf(a[3]) << 16);
  r.z = (unsigned)f2bf(b[0]) | ((unsigned)f2bf(b[1]) << 16);
  r.w = (unsigned)f2bf(b[2]) | ((unsigned)f2bf(b[3]) << 16);
  *(u32x4*)(out + (size_t)t * 8) = r;
}

// ---------------- W_red[m][j] = sum_{r<128} W_out[m][r*16+j] ----------------
__global__ __launch_bounds__(256) void k_wred(const float* __restrict__ wout,
                                              float* __restrict__ wred) {
  int t = blockIdx.x * 256 + threadIdx.x;   // 16384 threads
  int m = t >> 4, j = t & 15;
  float s = 0.f;
  for (int r = 0; r < 128; r++) s += wout[(size_t)m * 2048 + r * 16 + j];
  wred[t] = s;
}

// ---------------- bf16 NT MFMA GEMM core: C[M,N] = A[M,K] * B[N,K]^T --------
// 128x128 tile, BK=64, 4 waves (2x2), mfma_f32_16x16x32_bf16, linear LDS,
// global_load_lds width=16 (m97 structure).
template <int EPI>
DEVFN void gemm128(const unsigned short* __restrict__ Ag,
                   const unsigned short* __restrict__ Bg, int K,
                   int m0, int n0, const float* __restrict__ bias,
                   float* __restrict__ outf, unsigned short* __restrict__ outbf) {
  __shared__ unsigned short As[128 * 64];
  __shared__ unsigned short Bs[128 * 64];
  const int tid = threadIdx.x;
  const int wave = tid >> 6, lane = tid & 63;
  const int wm = wave >> 1, wn = wave & 1;
  const int fr = lane & 15;            // row-within-16 of A/B fragment
  const int k8 = (lane >> 4) << 3;     // k offset (8 contiguous bf16 per lane)

  f32x4 acc[4][4];
#pragma unroll
  for (int a = 0; a < 4; a++)
#pragma unroll
    for (int b = 0; b < 4; b++) acc[a][b] = f32x4{0.f, 0.f, 0.f, 0.f};

  for (int kt = 0; kt < K; kt += 64) {
#pragma unroll
    for (int i = 0; i < 4; i++) {
      const int base = (wave << 10) + (i << 12);      // byte offset in 16KB tile
      const int off = base + (lane << 4);
      const int row = off >> 7;
      const int col = (off & 127) >> 1;
      gload_lds16(Ag + (size_t)(m0 + row) * K + kt + col, (char*)As + base);
      gload_lds16(Bg + (size_t)(n0 + row) * K + kt + col, (char*)Bs + base);
    }
    __syncthreads();   // drains vmcnt before barrier (compiler-inserted)
#pragma unroll
    for (int kk = 0; kk < 2; kk++) {
      bf16x8 af[4], bfr[4];
#pragma unroll
      for (int f = 0; f < 4; f++) {
        af[f]  = *(const bf16x8*)&As[(wm * 64 + f * 16 + fr) * 64 + kk * 32 + k8];
        bfr[f] = *(const bf16x8*)&Bs[(wn * 64 + f * 16 + fr) * 64 + kk * 32 + k8];
      }
#pragma unroll
      for (int fi = 0; fi < 4; fi++)
#pragma unroll
        for (int fj = 0; fj < 4; fj++)
          acc[fi][fj] = __builtin_amdgcn_mfma_f32_16x16x32_bf16(
              af[fi], bfr[fj], acc[fi][fj], 0, 0, 0);
    }
    __syncthreads();
  }

  // epilogue: C/D layout col=lane&15, row=(lane>>4)*4+r (m89-verified)
  const int r0 = (lane >> 4) * 4;
#pragma unroll
  for (int fj = 0; fj < 4; fj++) {
    const int col = n0 + wn * 64 + fj * 16 + fr;
    const float bia = (EPI == 0) ? bias[col] : 0.f;
#pragma unroll
    for (int fi = 0; fi < 4; fi++) {
      const int rowb = m0 + wm * 64 + fi * 16 + r0;
#pragma unroll
      for (int r = 0; r < 4; r++) {
        const float v = acc[fi][fj][r] + bia;
        if (EPI == 0) {
          // split: cols [0,2048) -> xi (f32); [2048,4096) -> res (bf16)
          if (col < 2048) outf[(size_t)(rowb + r) * 2048 + col] = v;
          else            outbf[(size_t)(rowb + r) * 2048 + (col - 2048)] = f2bf(v);
        } else {
          outf[(size_t)(rowb + r) * 1024 + col] = v;
        }
      }
    }
  }
}

// K1: in_proj  C1 = x_bf @ W_in^T + b_in, split-store xi / res
__global__ __launch_bounds__(256) void k_gemm1(const unsigned short* __restrict__ xbf,
                                               const unsigned short* __restrict__ winbf,
                                               const float* __restrict__ b_in,
                                               float* __restrict__ xi,
                                               unsigned short* __restrict__ resbf) {
  const int bid = blockIdx.x;                // 64 x 32 tiles
  gemm128<0>(xbf, winbf, 1024, (bid >> 5) * 128, (bid & 31) * 128, b_in, xi, resbf);
}

// K2: depthwise causal conv (K=4) + silu; xi f32 -> xs bf16
__global__ __launch_bounds__(256) void k_conv(const float* __restrict__ xi,
                                              const float* __restrict__ cw,
                                              const float* __restrict__ cb,
                                              unsigned short* __restrict__ xs) {
  const int t = blockIdx.x * 256 + threadIdx.x;
  const int c4 = t & 511;                 // 512 channel-quads
  const int lc = (t >> 9) & 255;          // 256 l-chunks of 8
  const int b  = t >> 17;                 // 4 batches
  const int l0 = lc * 8;
  const int c0 = c4 * 4;
  const float* xb = xi + ((size_t)(b * 2048 + l0)) * 2048 + c0;
  const f32x4 Z = {0.f, 0.f, 0.f, 0.f};
  f32x4 val[11];
#pragma unroll
  for (int j = 0; j < 11; j++) {
    const int l = l0 + j - 3;
    val[j] = (l >= 0) ? *(const f32x4*)(xb + ((long)j - 3) * 2048) : Z;
  }
  const f32x4 w0 = *(const f32x4*)(cw + (size_t)c0 * 4);
  const f32x4 w1 = *(const f32x4*)(cw + (size_t)(c0 + 1) * 4);
  const f32x4 w2 = *(const f32x4*)(cw + (size_t)(c0 + 2) * 4);
  const f32x4 w3 = *(const f32x4*)(cw + (size_t)(c0 + 3) * 4);
  const f32x4 bb = *(const f32x4*)(cb + c0);
  unsigned short* xp = xs + ((size_t)(b * 2048 + l0)) * 2048 + c0;
#pragma unroll
  for (int jo = 0; jo < 8; jo++) {
    f32x4 v;
    v[0] = bb[0] + w0[0]*val[jo][0] + w0[1]*val[jo+1][0] + w0[2]*val[jo+2][0] + w0[3]*val[jo+3][0];
    v[1] = bb[1] + w1[0]*val[jo][1] + w1[1]*val[jo+1][1] + w1[2]*val[jo+2][1] + w1[3]*val[jo+3][1];
    v[2] = bb[2] + w2[0]*val[jo][2] + w2[1]*val[jo+1][2] + w2[2]*val[jo+2][2] + w2[3]*val[jo+3][2];
    v[3] = bb[3] + w3[0]*val[jo][3] + w3[1]*val[jo+1][3] + w3[2]*val[jo+2][3] + w3[3]*val[jo+3][3];
#pragma unroll
    for (int q = 0; q < 4; q++) {
      const float x = v[q];
      v[q] = x * __builtin_amdgcn_rcpf(1.f + __expf(-x));   // silu
    }
    u32x2 rr;
    rr.x = (unsigned)f2bf(v[0]) | ((unsigned)f2bf(v[1]) << 16);
    rr.y = (unsigned)f2bf(v[2]) | ((unsigned)f2bf(v[3]) << 16);
    *(u32x2*)(xp + (size_t)jo * 2048) = rr;
  }
}

// K3: x_proj  bc = xs @ W_x^T + b_x   (M=8192, N=32, K=2048)
__global__ __launch_bounds__(256) void k_gemm2(const unsigned short* __restrict__ xs,
                                               const unsigned short* __restrict__ wx,
                                               const float* __restrict__ bx,
                                               float* __restrict__ bc) {
  __shared__ unsigned short As[128 * 64];
  __shared__ unsigned short Bs[32 * 64];
  const int tid = threadIdx.x, wave = tid >> 6, lane = tid & 63;
  const int m0 = blockIdx.x * 128;
  const int fr = lane & 15, k8 = (lane >> 4) << 3;
  f32x4 acc[2][2];
#pragma unroll
  for (int a = 0; a < 2; a++)
#pragma unroll
    for (int b = 0; b < 2; b++) acc[a][b] = f32x4{0.f, 0.f, 0.f, 0.f};

  for (int kt = 0; kt < 2048; kt += 64) {
#pragma unroll
    for (int i = 0; i < 4; i++) {
      const int base = (wave << 10) + (i << 12);
      const int off = base + (lane << 4);
      const int row = off >> 7, col = (off & 127) >> 1;
      gload_lds16(xs + (size_t)(m0 + row) * 2048 + kt + col, (char*)As + base);
    }
    {
      const int base = (wave << 10);
      const int off = base + (lane << 4);
      const int row = off >> 7, col = (off & 127) >> 1;
      gload_lds16(wx + (size_t)row * 2048 + kt + col, (char*)Bs + base);
    }
    __syncthreads();
#pragma unroll
    for (int kk = 0; kk < 2; kk++) {
      bf16x8 af[2], bfr[2];
#pragma unroll
      for (int f = 0; f < 2; f++) {
        af[f]  = *(const bf16x8*)&As[(wave * 32 + f * 16 + fr) * 64 + kk * 32 + k8];
        bfr[f] = *(const bf16x8*)&Bs[(f * 16 + fr) * 64 + kk * 32 + k8];
      }
#pragma unroll
      for (int fi = 0; fi < 2; fi++)
#pragma unroll
        for (int fj = 0; fj < 2; fj++)
          acc[fi][fj] = __builtin_amdgcn_mfma_f32_16x16x32_bf16(
              af[fi], bfr[fj], acc[fi][fj], 0, 0, 0);
    }
    __syncthreads();
  }
  const int r0 = (lane >> 4) * 4;
#pragma unroll
  for (int fi = 0; fi < 2; fi++)
#pragma unroll
    for (int fj = 0; fj < 2; fj++) {
      const int col = fj * 16 + fr;
      const float bia = bx[col];
#pragma unroll
      for (int r = 0; r < 4; r++) {
        const int row = m0 + wave * 32 + fi * 16 + r0 + r;
        bc[(size_t)row * 32 + col] = acc[fi][fj][r] + bia;
      }
    }
}

// ---------------- scan step: h' = tanh(A_t h + B*h + C) ----------------
DEVFN float scan_step(float h, int l, float Bt, float Ct,
                      const float* __restrict__ Ae, int lane, int i) {
  const int p = l & 15;
  const float* ar = Ae + p * 256 + i * 16;
  const f32x4 a0 = *(const f32x4*)(ar + 0);
  const f32x4 a1 = *(const f32x4*)(ar + 4);
  const f32x4 a2 = *(const f32x4*)(ar + 8);
  const f32x4 a3 = *(const f32x4*)(ar + 12);
  const int gb = lane & 48;
  const float h0 = __shfl(h, gb + 0),  h1 = __shfl(h, gb + 1);
  const float h2 = __shfl(h, gb + 2),  h3 = __shfl(h, gb + 3);
  const float h4 = __shfl(h, gb + 4),  h5 = __shfl(h, gb + 5);
  const float h6 = __shfl(h, gb + 6),  h7 = __shfl(h, gb + 7);
  const float h8 = __shfl(h, gb + 8),  h9 = __shfl(h, gb + 9);
  const float hA = __shfl(h, gb + 10), hB = __shfl(h, gb + 11);
  const float hC = __shfl(h, gb + 12), hD = __shfl(h, gb + 13);
  const float hE = __shfl(h, gb + 14), hF = __shfl(h, gb + 15);
  const float s0 = a0[0]*h0 + a0[1]*h1 + a0[2]*h2 + a0[3]*h3;
  const float s1 = a1[0]*h4 + a1[1]*h5 + a1[2]*h6 + a1[3]*h7;
  const float s2 = a2[0]*h8 + a2[1]*h9 + a2[2]*hA + a2[3]*hB;
  const float s3 = a3[0]*hC + a3[1]*hD + a3[2]*hE + a3[3]*hF;
  const float s = ((s0 + s1) + (s2 + s3)) + Bt * h + Ct;
  // tanh(s) = 1 - 2/(exp(2s)+1); exp->inf / ->0 give +-1 correctly
  const float e = __expf(2.f * s);
  return 1.f - 2.f * __builtin_amdgcn_rcpf(e + 1.f);
}

// K4: fused  [blocks 0..511]: out = res_bf @ W_out^T   (MFMA)
//            [block 512, wave 0]: sequential selective scan -> hs
__global__ __launch_bounds__(256) void k4_gemm3_scan(
    const unsigned short* __restrict__ resbf, const unsigned short* __restrict__ woutbf,
    float* __restrict__ out, const float* __restrict__ bc, const float* __restrict__ dt,
    const float* __restrict__ Amat, float* __restrict__ hs) {
  if (blockIdx.x < 512) {
    const int bid = blockIdx.x;              // 64 x 8 tiles
    gemm128<1>(resbf, woutbf, 2048, (bid >> 3) * 128, (bid & 7) * 128, nullptr, out, nullptr);
    return;
  }
  __shared__ float Ae[16 * 16 * 16];         // [p][i][j] = exp(exp(dt[p])*A[i][j])
  if (threadIdx.x >= 64) return;             // single wave does the scan
  const int lane = threadIdx.x, b = lane >> 4, i = lane & 15;
  for (int t = lane; t < 4096; t += 64)
    Ae[t] = __expf(__expf(dt[t >> 8]) * Amat[t & 255]);
  asm volatile("s_waitcnt lgkmcnt(0)" ::: "memory");
  __builtin_amdgcn_wave_barrier();

  const float* bcp = bc + (size_t)b * 2048 * 32 + i;   // B at [l*32], C at [l*32+16]
  float* hsp = hs + (size_t)b * 2048 * 16 + i;
  float h = 0.f;
  float B0 = bcp[0],  C0 = bcp[16], B1 = bcp[32], C1 = bcp[48];
  float B2 = bcp[64], C2 = bcp[80], B3 = bcp[96], C3 = bcp[112];
  for (int l0 = 0; l0 < 2048; l0 += 4) {
    const int lp = (l0 + 4) & 2047;          // wrap: values unused on last iter
    const float* pf = bcp + (size_t)lp * 32;
    const float nB0 = pf[0],  nC0 = pf[16], nB1 = pf[32], nC1 = pf[48];
    const float nB2 = pf[64], nC2 = pf[80], nB3 = pf[96], nC3 = pf[112];
    h = scan_step(h, l0 + 0, B0, C0, Ae, lane, i); hsp[(size_t)(l0 + 0) * 16] = h;
    h = scan_step(h, l0 + 1, B1, C1, Ae, lane, i); hsp[(size_t)(l0 + 1) * 16] = h;
    h = scan_step(h, l0 + 2, B2, C2, Ae, lane, i); hsp[(size_t)(l0 + 2) * 16] = h;
    h = scan_step(h, l0 + 3, B3, C3, Ae, lane, i); hsp[(size_t)(l0 + 3) * 16] = h;
    B0 = nB0; C0 = nC0; B1 = nB1; C1 = nC1; B2 = nB2; C2 = nC2; B3 = nB3; C3 = nC3;
  }
}

// K5: out += b_out + hs @ W_red^T   (tile(hs,128) @ W_out^T == hs @ W_red^T)
__global__ __launch_bounds__(256) void k5_combine(float* __restrict__ out,
                                                  const float* __restrict__ hs,
                                                  const float* __restrict__ wred,
                                                  const float* __restrict__ bo) {
  const int m4 = threadIdx.x;      // 256 col-quads
  const int rg = blockIdx.x;       // 2048 row-quads
  f32x4 w[4][4];
#pragma unroll
  for (int mi = 0; mi < 4; mi++)
#pragma unroll
    for (int q = 0; q < 4; q++)
      w[mi][q] = *(const f32x4*)&wred[(size_t)(m4 * 4 + mi) * 16 + q * 4];
  const f32x4 bov = *(const f32x4*)&bo[m4 * 4];
#pragma unroll
  for (int r = 0; r < 4; r++) {
    const size_t row = (size_t)rg * 4 + r;
    f32x4 hv[4];
#pragma unroll
    for (int q = 0; q < 4; q++) hv[q] = *(const f32x4*)&hs[row * 16 + q * 4];
    float* op = out + row * 1024 + m4 * 4;
    f32x4 o = *(f32x4*)op;
#pragma unroll
    for (int mi = 0; mi < 4; mi++) {
      float v = bov[mi];
#pragma unroll
      for (int q = 0; q < 4; q++)
        v += w[mi][q][0]*hv[q][0] + w[mi][q][1]*hv[q][1] +
             w[mi][q][2]*hv[q][2] + w[mi][q][3]*hv[q][3];
      o[mi] += v;
    }
    *(f32x4*)op = o;
  }
}

extern "C" void kernel_launch(void* const* d_in, const int* in_sizes, int n_in,
                              void* d_out, int out_size, void* d_ws, size_t ws_size,
                              hipStream_t stream) {
  const float* x      = (const float*)d_in[0];
  const float* W_in   = (const float*)d_in[1];
  const float* b_in   = (const float*)d_in[2];
  const float* conv_w = (const float*)d_in[3];
  const float* conv_b = (const float*)d_in[4];
  const float* W_x    = (const float*)d_in[5];
  const float* b_x    = (const float*)d_in[6];
  const float* dt     = (const float*)d_in[7];
  const float* A      = (const float*)d_in[8];
  const float* W_out  = (const float*)d_in[10];
  const float* b_out  = (const float*)d_in[11];
  float* out = (float*)d_out;

  char* ws = (char*)d_ws;
  unsigned short* xbf    = (unsigned short*)(ws + OFF_XBF);
  unsigned short* winbf  = (unsigned short*)(ws + OFF_WINBF);
  unsigned short* wxbf   = (unsigned short*)(ws + OFF_WXBF);
  unsigned short* woutbf = (unsigned short*)(ws + OFF_WOUTBF);
  float*          wred   = (float*)(ws + OFF_WRED);
  float*          xi     = (float*)(ws + OFF_XI);
  unsigned short* resbf  = (unsigned short*)(ws + OFF_RESBF);
  unsigned short* xsbf   = (unsigned short*)(ws + OFF_XSBF);
  float*          bc     = (float*)(ws + OFF_BC);
  float*          hsb    = (float*)(ws + OFF_HS);

  k_f2bf<<<4096, 256, 0, stream>>>(x, xbf, 1048576);      // 8192x1024
  k_f2bf<<<2048, 256, 0, stream>>>(W_in, winbf, 524288);  // 4096x1024
  k_f2bf<<<32,   256, 0, stream>>>(W_x, wxbf, 8192);      // 32x2048
  k_f2bf<<<1024, 256, 0, stream>>>(W_out, woutbf, 262144);// 1024x2048
  k_wred<<<64, 256, 0, stream>>>(W_out, wred);

  k_gemm1<<<2048, 256, 0, stream>>>(xbf, winbf, b_in, xi, resbf);
  k_conv<<<2048, 256, 0, stream>>>(xi, conv_w, conv_b, xsbf);
  k_gemm2<<<64, 256, 0, stream>>>(xsbf, wxbf, b_x, bc);
  k4_gemm3_scan<<<513, 256, 0, stream>>>(resbf, woutbf, out, bc, dt, A, hsb);
  k5_combine<<<2048, 256, 0, stream>>>(out, hsb, wred, b_out);
}